// Round 13
// baseline (70.461 us; speedup 1.0000x reference)
//
#include <hip/hip_runtime.h>

#define NMAX 10
#define NP   8           // f2 unit-pairs per lane per MLP (16 units = 8 x f2)
#define L2E  1.4426950408889634f
#define LN2  0.6931471805599453f
#define NBLK 1024        // persistent: 4 blocks/CU x 256 CUs, all resident

typedef float f2 __attribute__((ext_vector_type(2)));

// ---------- DPP cross-lane sum (VALU pipe only) ----------
template<int CTRL, int RMASK, int BMASK>
__device__ __forceinline__ float dppmov(float v) {
    return __int_as_float(__builtin_amdgcn_update_dpp(
        0, __float_as_int(v), CTRL, RMASK, BMASK, true));
}
__device__ __forceinline__ float rdlane63(float v) {
    return __int_as_float(__builtin_amdgcn_readlane(__float_as_int(v), 63));
}

// one wave64 sum -> uniform scalar
__device__ __forceinline__ float wred1(float a) {
    a += dppmov<0xB1, 0xf, 0xf>(a);   // quad xor1
    a += dppmov<0x4E, 0xf, 0xf>(a);   // quad xor2
    a += dppmov<0x141,0xf, 0xf>(a);   // half-row mirror (xor4)
    a += dppmov<0x140,0xf, 0xf>(a);   // row mirror (xor8)
    a += dppmov<0x142,0xa, 0xf>(a);   // row_bcast15 -> rows 1,3
    a += dppmov<0x143,0xc, 0xf>(a);   // row_bcast31 -> rows 2,3
    return rdlane63(a);
}

// One f2 unit-pair, pre-scaled ELU-dot step (bit-identical to rounds 8-12):
//   p' = pk_fma(wy', y, u');  e = exp2(p');  z = pk_fma(e, L2E, -L2E);
//   m = med3(p', z, 0) = L2E*elu(p);  acc = pk_fma(w2', m, acc).
__device__ __forceinline__ void unit_step(const f2 wy, const f2 w2,
                                          const f2 u, const f2 yv, f2& acc) {
    const f2 l2e  = {L2E, L2E};
    const f2 nl2e = {-L2E, -L2E};
    f2 p = __builtin_elementwise_fma(wy, yv, u);     // v_pk_fma_f32
    f2 e;
    e.x = __builtin_amdgcn_exp2f(p.x);  e.y = __builtin_amdgcn_exp2f(p.y);
    f2 z = __builtin_elementwise_fma(e, l2e, nl2e);  // v_pk_fma_f32
    f2 m;
    m.x = __builtin_amdgcn_fmed3f(p.x, z.x, 0.f);
    m.y = __builtin_amdgcn_fmed3f(p.y, z.y, 0.f);
    acc = __builtin_elementwise_fma(w2, m, acc);     // v_pk_fma_f32
}

// single-MLP eval: 8 f2 unit-pairs from LDS float4 {wy_lo, wy_hi, w2_lo, w2_hi}
__device__ __forceinline__ float mlp_one(
    const float4* __restrict__ wl,   // &wlds[mlp_base + lane], stride 64/pair
    const f2 (&u)[NP], float y, float bias)
{
    const f2 yv = {y, y};
    f2 acc0 = {0.f, 0.f}, acc1 = {0.f, 0.f};
#pragma unroll
    for (int p = 0; p < NP; p += 2) {
        const float4 wa = wl[p * 64];
        const float4 wb = wl[(p + 1) * 64];
        unit_step((f2){wa.x, wa.y}, (f2){wa.z, wa.w}, u[p],     yv, acc0);
        unit_step((f2){wb.x, wb.y}, (f2){wb.z, wb.w}, u[p + 1], yv, acc1);
    }
    f2 acc = acc0 + acc1;
    return wred1(acc.x + acc.y) + bias;
}

__global__ __launch_bounds__(256) void rmodel_kernel(
    const float* __restrict__ X, const float* __restrict__ Y,
    const float* __restrict__ de_W1, const float* __restrict__ de_b1,
    const float* __restrict__ de_W2, const float* __restrict__ de_b2,
    const float* __restrict__ val_W1, const float* __restrict__ val_b1,
    const float* __restrict__ val_W2, const float* __restrict__ val_b2,
    float* __restrict__ out, int n)
{
    // 16 KB: [0..511] = val-MLP unit-pairs, [512..1023] = de-MLP unit-pairs.
    // entry e = p*64 + lane: units h0 = lane + 128p, h1 = h0 + 64.
    __shared__ float4 wlds[2 * NP * 64];

    const int tid  = threadIdx.x;
    const int wid  = tid >> 6;
    const int lane = tid & 63;

    // ---- cooperative LDS fill (once per persistent block) ----
#pragma unroll
    for (int i = 0; i < 4; ++i) {
        const int e  = tid + i * 256;        // 0..1023
        const int a  = e >> 9;               // 0 = val, 1 = de
        const int ei = e & 511;
        const int p  = ei >> 6, l = ei & 63;
        const int h0 = l + (p << 7), h1 = h0 + 64;
        const float* W1 = a ? de_W1 : val_W1;
        const float* W2 = a ? de_W2 : val_W2;
        wlds[e] = make_float4(W1[2 * h0 + 1] * L2E, W1[2 * h1 + 1] * L2E,
                              W2[h0] * LN2,         W2[h1] * LN2);
    }
    __syncthreads();

    const float db2 = de_b2[0];
    const float vb2 = val_b2[0];
    const float4* wlv = &wlds[lane];         // val-MLP base
    const float4* wld = &wlds[512 + lane];   // de-MLP base

    float* __restrict__ yout = out;                       // [NMAX+1][n]
    float* __restrict__ vout = out + (size_t)(NMAX + 1) * n;

    const int gw = blockIdx.x * 4 + wid;     // global wave id
    const int GW = NBLK * 4;                 // 4096 resident waves

    // ---- persistent: each wave serially handles n/GW samples (tail-averaging) ----
    for (int b = gw; b < n; b += GW) {
        // per-sample state: u[] only (pre-scaled, x-hoisted)
        f2 uv[NP], ud[NP];
        const float x  = X[b];
        const float y0 = Y[b];
#pragma unroll
        for (int p = 0; p < NP; ++p) {
            const int h0 = lane + (p << 7), h1 = h0 + 64;
            uv[p] = (f2){fmaf(val_W1[2 * h0], x, val_b1[h0]) * L2E,
                         fmaf(val_W1[2 * h1], x, val_b1[h1]) * L2E};
            ud[p] = (f2){fmaf(de_W1[2 * h0], x, de_b1[h0]) * L2E,
                         fmaf(de_W1[2 * h1], x, de_b1[h1]) * L2E};
        }

        // ---- split chain: val pass -> break check -> de pass only if needed ----
        float v = mlp_one(wlv, uv, y0, vb2);              // v0
        if (lane == 0) { yout[b] = y0; vout[b] = v; }

        float y     = y0 + mlp_one(wld, ud, y0, db2);     // y1 (de always needed)
        float vprev = v;
        float yfin  = y0, vfin = v;
        int   kend  = NMAX;

        float* yp = yout + b;
        float* vp = vout + b;
        for (int k = 1; k <= NMAX; ++k) {
            yp += n; vp += n;
            const float vk = mlp_one(wlv, uv, y, vb2);    // val(y_k)
            if (lane == 0) { *yp = y; *vp = vk; }
            yfin = y; vfin = vk;
            if (k >= 2 && vk >= vprev) { kend = k; break; }  // ref: i>0 && v_new >= v_prev
            vprev = vk;
            if (k < NMAX) y += mlp_one(wld, ud, y, db2);  // de only if continuing
        }

        // ---- frozen rows: lanes store in parallel ----
        const int r = kend + 1 + lane;
        if (r <= NMAX) {
            yout[(size_t)r * n + b] = yfin;
            vout[(size_t)r * n + b] = vfin;
        }
    }
}

extern "C" void kernel_launch(void* const* d_in, const int* in_sizes, int n_in,
                              void* d_out, int out_size, void* d_ws, size_t ws_size,
                              hipStream_t stream) {
    const float* X      = (const float*)d_in[0];
    const float* Y      = (const float*)d_in[1];
    const float* de_W1  = (const float*)d_in[2];
    const float* de_b1  = (const float*)d_in[3];
    const float* de_W2  = (const float*)d_in[4];
    const float* de_b2  = (const float*)d_in[5];
    const float* val_W1 = (const float*)d_in[6];
    const float* val_b1 = (const float*)d_in[7];
    const float* val_W2 = (const float*)d_in[8];
    const float* val_b2 = (const float*)d_in[9];
    float* out = (float*)d_out;

    const int n = in_sizes[0];               // 16384 samples
    dim3 block(256);                          // 4 waves/block, 1 wave = 1 sample
    dim3 grid(NBLK);                          // persistent: all blocks resident
    hipLaunchKernelGGL(rmodel_kernel, grid, block, 0, stream,
                       X, Y, de_W1, de_b1, de_W2, de_b2,
                       val_W1, val_b1, val_W2, val_b2, out, n);
}

// Round 14
// 64.899 us; speedup vs baseline: 1.0857x; 1.0857x over previous
//
#include <hip/hip_runtime.h>

#define NMAX 10
#define NP   8           // f2 unit-pairs per lane per MLP (16 units = 8 x f2)
#define L2E  1.4426950408889634f
#define LN2  0.6931471805599453f

typedef float f2 __attribute__((ext_vector_type(2)));

// ---------- DPP cross-lane sum (VALU pipe only) ----------
template<int CTRL, int RMASK, int BMASK>
__device__ __forceinline__ float dppmov(float v) {
    return __int_as_float(__builtin_amdgcn_update_dpp(
        0, __float_as_int(v), CTRL, RMASK, BMASK, true));
}
__device__ __forceinline__ float rdlane63(float v) {
    return __int_as_float(__builtin_amdgcn_readlane(__float_as_int(v), 63));
}

// one wave64 sum -> uniform scalar
__device__ __forceinline__ float wred1(float a) {
    a += dppmov<0xB1, 0xf, 0xf>(a);   // quad xor1
    a += dppmov<0x4E, 0xf, 0xf>(a);   // quad xor2
    a += dppmov<0x141,0xf, 0xf>(a);   // half-row mirror (xor4)
    a += dppmov<0x140,0xf, 0xf>(a);   // row mirror (xor8)
    a += dppmov<0x142,0xa, 0xf>(a);   // row_bcast15 -> rows 1,3
    a += dppmov<0x143,0xc, 0xf>(a);   // row_bcast31 -> rows 2,3
    return rdlane63(a);
}

// One f2 unit-pair, pre-scaled ELU-dot step (bit-identical to rounds 8-12):
//   p' = pk_fma(wy', y, u');  e = exp2(p');  z = pk_fma(e, L2E, -L2E);
//   m = med3(p', z, 0) = L2E*elu(p);  acc = pk_fma(w2', m, acc).
__device__ __forceinline__ void unit_step(const f2 wy, const f2 w2,
                                          const f2 u, const f2 yv, f2& acc) {
    const f2 l2e  = {L2E, L2E};
    const f2 nl2e = {-L2E, -L2E};
    f2 p = __builtin_elementwise_fma(wy, yv, u);     // v_pk_fma_f32
    f2 e;
    e.x = __builtin_amdgcn_exp2f(p.x);  e.y = __builtin_amdgcn_exp2f(p.y);
    f2 z = __builtin_elementwise_fma(e, l2e, nl2e);  // v_pk_fma_f32
    f2 m;
    m.x = __builtin_amdgcn_fmed3f(p.x, z.x, 0.f);
    m.y = __builtin_amdgcn_fmed3f(p.y, z.y, 0.f);
    acc = __builtin_elementwise_fma(w2, m, acc);     // v_pk_fma_f32
}

// single-MLP eval: 8 f2 unit-pairs from LDS float4 {wy_lo, wy_hi, w2_lo, w2_hi}
__device__ __forceinline__ float mlp_one(
    const float4* __restrict__ wl,   // &wlds[mlp_base + lane], stride 64/pair
    const f2 (&u)[NP], float y, float bias)
{
    const f2 yv = {y, y};
    f2 acc0 = {0.f, 0.f}, acc1 = {0.f, 0.f};
#pragma unroll
    for (int p = 0; p < NP; p += 2) {
        const float4 wa = wl[p * 64];
        const float4 wb = wl[(p + 1) * 64];
        unit_step((f2){wa.x, wa.y}, (f2){wa.z, wa.w}, u[p],     yv, acc0);
        unit_step((f2){wb.x, wb.y}, (f2){wb.z, wb.w}, u[p + 1], yv, acc1);
    }
    f2 acc = acc0 + acc1;
    return wred1(acc.x + acc.y) + bias;
}

__global__ __launch_bounds__(256) void rmodel_kernel(
    const float* __restrict__ X, const float* __restrict__ Y,
    const float* __restrict__ de_W1, const float* __restrict__ de_b1,
    const float* __restrict__ de_W2, const float* __restrict__ de_b2,
    const float* __restrict__ val_W1, const float* __restrict__ val_b1,
    const float* __restrict__ val_W2, const float* __restrict__ val_b2,
    float* __restrict__ out, int n)
{
    // 16 KB: [0..511] = val-MLP unit-pairs, [512..1023] = de-MLP unit-pairs.
    // entry e = p*64 + lane: units h0 = lane + 128p, h1 = h0 + 64.
    __shared__ float4 wlds[2 * NP * 64];

    const int tid  = threadIdx.x;
    const int wid  = tid >> 6;
    const int lane = tid & 63;

    // ---- cooperative LDS fill: sample-invariant pre-scaled weights ----
#pragma unroll
    for (int i = 0; i < 4; ++i) {
        const int e  = tid + i * 256;        // 0..1023
        const int a  = e >> 9;               // 0 = val, 1 = de
        const int ei = e & 511;
        const int p  = ei >> 6, l = ei & 63;
        const int h0 = l + (p << 7), h1 = h0 + 64;
        const float* W1 = a ? de_W1 : val_W1;
        const float* W2 = a ? de_W2 : val_W2;
        wlds[e] = make_float4(W1[2 * h0 + 1] * L2E, W1[2 * h1 + 1] * L2E,
                              W2[h0] * LN2,         W2[h1] * LN2);
    }
    __syncthreads();

    const int b = blockIdx.x * 4 + wid;      // one wave = one sample
    if (b >= n) return;

    // ---- per-sample state: u[] only (pre-scaled, x-hoisted) ----
    f2 uv[NP], ud[NP];
    const float x  = X[b];
    const float y0 = Y[b];
#pragma unroll
    for (int p = 0; p < NP; ++p) {
        const int h0 = lane + (p << 7), h1 = h0 + 64;
        uv[p] = (f2){fmaf(val_W1[2 * h0], x, val_b1[h0]) * L2E,
                     fmaf(val_W1[2 * h1], x, val_b1[h1]) * L2E};
        ud[p] = (f2){fmaf(de_W1[2 * h0], x, de_b1[h0]) * L2E,
                     fmaf(de_W1[2 * h1], x, de_b1[h1]) * L2E};
    }
    const float db2 = de_b2[0];
    const float vb2 = val_b2[0];
    const float4* wlv = &wlds[lane];         // val-MLP base
    const float4* wld = &wlds[512 + lane];   // de-MLP base

    float* __restrict__ yout = out;                       // [NMAX+1][n]
    float* __restrict__ vout = out + (size_t)(NMAX + 1) * n;

    // ---- split chain: val pass -> break check -> de pass only if needed ----
    float v = mlp_one(wlv, uv, y0, vb2);                  // v0
    if (lane == 0) { yout[b] = y0; vout[b] = v; }

    float y     = y0 + mlp_one(wld, ud, y0, db2);         // y1 (de always needed)
    float vprev = v;
    float yfin  = y0, vfin = v;
    int   kend  = NMAX;

    float* yp = yout + b;
    float* vp = vout + b;
    for (int k = 1; k <= NMAX; ++k) {
        yp += n; vp += n;
        const float vk = mlp_one(wlv, uv, y, vb2);        // val(y_k)
        if (lane == 0) { *yp = y; *vp = vk; }
        yfin = y; vfin = vk;
        if (k >= 2 && vk >= vprev) { kend = k; break; }   // ref: i>0 && v_new >= v_prev
        vprev = vk;
        if (k < NMAX) y += mlp_one(wld, ud, y, db2);      // de only if continuing
    }

    // ---- frozen rows: lanes store in parallel ----
    const int r = kend + 1 + lane;
    if (r <= NMAX) {
        yout[(size_t)r * n + b] = yfin;
        vout[(size_t)r * n + b] = vfin;
    }
}

extern "C" void kernel_launch(void* const* d_in, const int* in_sizes, int n_in,
                              void* d_out, int out_size, void* d_ws, size_t ws_size,
                              hipStream_t stream) {
    const float* X      = (const float*)d_in[0];
    const float* Y      = (const float*)d_in[1];
    const float* de_W1  = (const float*)d_in[2];
    const float* de_b1  = (const float*)d_in[3];
    const float* de_W2  = (const float*)d_in[4];
    const float* de_b2  = (const float*)d_in[5];
    const float* val_W1 = (const float*)d_in[6];
    const float* val_b1 = (const float*)d_in[7];
    const float* val_W2 = (const float*)d_in[8];
    const float* val_b2 = (const float*)d_in[9];
    float* out = (float*)d_out;

    const int n = in_sizes[0];               // 16384 samples
    dim3 block(256);                          // 4 waves/block, 1 wave = 1 sample
    dim3 grid((n + 3) / 4);
    hipLaunchKernelGGL(rmodel_kernel, grid, block, 0, stream,
                       X, Y, de_W1, de_b1, de_W2, de_b2,
                       val_W1, val_b1, val_W2, val_b2, out, n);
}